// Round 1
// baseline (1281.731 us; speedup 1.0000x reference)
//
#include <hip/hip_runtime.h>
#include <math.h>

#define HD 64
#define WPB 4   // waves (graphs) per block

__device__ __forceinline__ float wsum64(float v) {
#pragma unroll
  for (int s = 32; s > 0; s >>= 1) v += __shfl_xor(v, s, 64);
  return v;
}

// acc[r] += sum_k xb[r*64+k] * W[k*64+t]   (xb in LDS, W in global)
template <int R>
__device__ __forceinline__ void mmk(const float* xb, const float* __restrict__ W,
                                    int t, float* acc) {
#pragma unroll 2
  for (int k = 0; k < 64; k += 4) {
    const float w0 = W[(k + 0) * HD + t];
    const float w1 = W[(k + 1) * HD + t];
    const float w2 = W[(k + 2) * HD + t];
    const float w3 = W[(k + 3) * HD + t];
#pragma unroll
    for (int r = 0; r < R; ++r) {
      const float4 xv = *reinterpret_cast<const float4*>(xb + r * HD + k);
      float a = acc[r];
      a = fmaf(xv.x, w0, a);
      a = fmaf(xv.y, w1, a);
      a = fmaf(xv.z, w2, a);
      a = fmaf(xv.w, w3, a);
      acc[r] = a;
    }
  }
}

__global__ __launch_bounds__(64 * WPB) void egcl_fused(
    const float* __restrict__ gh, const float* __restrict__ gcoord,
    const float* __restrict__ gvel,
    const float* __restrict__ e_w1, const float* __restrict__ e_b1,
    const float* __restrict__ e_w2, const float* __restrict__ e_b2,
    const float* __restrict__ n_w1, const float* __restrict__ n_b1,
    const float* __restrict__ n_w2, const float* __restrict__ n_b2,
    const float* __restrict__ c_w1, const float* __restrict__ c_b1,
    const float* __restrict__ c_w2,
    const float* __restrict__ v_w1, const float* __restrict__ v_b1,
    const float* __restrict__ v_w2, const float* __restrict__ v_b2,
    const float* __restrict__ ic_wef, const float* __restrict__ ic_pat,
    const float* __restrict__ br_w1, const float* __restrict__ br_b1,
    const float* __restrict__ br_w2, const float* __restrict__ br_b2,
    const float* __restrict__ out_w, const float* __restrict__ out_b,
    float* __restrict__ hout, float* __restrict__ cout, int B) {
  __shared__ float xb0[WPB][25][HD];
  __shared__ float xb1[WPB][25][HD];
  __shared__ float hb[WPB][5][HD];
  __shared__ float efb[WPB][25][12];
  __shared__ float scv[WPB][32];  // [0..14]=coord, [16..30]=vel

  const int t = threadIdx.x & 63;
  const int wv = threadIdx.x >> 6;
  int g = blockIdx.x * WPB + wv;
  const bool active = (g < B);
  if (!active) g = B - 1;  // clamped tail wave still participates in barriers

  // ---------------- load coord / vel / h ----------------
  if (t < 15) scv[wv][t] = gcoord[g * 15 + t];
  if (t >= 16 && t < 31) scv[wv][t] = gvel[g * 15 + (t - 16)];
  float hreg[5];
#pragma unroll
  for (int i = 0; i < 5; ++i) {
    const float hv = gh[(g * 5 + i) * HD + t];
    hreg[i] = hv;
    hb[wv][i][t] = hv;
  }
  __syncthreads();

  // ---------------- RBF edge features: lane p<25 handles tuple (i,j) ------
  if (t < 25) {
    const int ti = t / 5, tj = t % 5;
    const float cix = scv[wv][ti * 3 + 0], ciy = scv[wv][ti * 3 + 1], ciz = scv[wv][ti * 3 + 2];
    const float cjx = scv[wv][tj * 3 + 0], cjy = scv[wv][tj * 3 + 1], cjz = scv[wv][tj * 3 + 2];
    const float vix = scv[wv][16 + ti * 3 + 0], viy = scv[wv][16 + ti * 3 + 1], viz = scv[wv][16 + ti * 3 + 2];
    const float vjx = scv[wv][16 + tj * 3 + 0], vjy = scv[wv][16 + tj * 3 + 1], vjz = scv[wv][16 + tj * 3 + 2];

    auto sdist = [](float ax, float ay, float az, float bx, float by, float bz) {
      const float dx = ax - bx, dy = ay - by, dz = az - bz;
      const float sq = dx * dx + dy * dy + dz * dz;
      return (sq > 0.0f) ? sqrtf(sq) : 0.0f;  // safe_pdist semantics
    };
    const float dcc = sdist(cix, ciy, ciz, cjx, cjy, cjz);
    const float dvv = sdist(vix, viy, viz, vjx, vjy, vjz);
    const float dcv = sdist(cix, ciy, ciz, vjx, vjy, vjz);  // mcd[i][j]
    const float dvc = sdist(cjx, cjy, cjz, vix, viy, viz);  // mcd[j][i]

    auto rbf3 = [&](float d, int base) {
      const float cut = (d <= 10.0f) ? (0.5f * (cosf(d * 0.31415926535897931f) + 1.0f)) : 0.0f;
      const float e = expf(-0.5f * d);
      const float u0 = e - 4.5399929762484854e-05f;  // mean0 = exp(-10)
      const float u1 = e - 0.50002270f;              // mean1
      const float u2 = e - 1.0f;                     // mean2
      const float BETA = 2.2502043f;
      efb[wv][t][base + 0] = (cut * expf(-BETA * u0 * u0) - 0.05f) * (1.0f / 0.15f);
      efb[wv][t][base + 1] = (cut * expf(-BETA * u1 * u1) - 0.05f) * (1.0f / 0.15f);
      efb[wv][t][base + 2] = (cut * expf(-BETA * u2 * u2) - 0.05f) * (1.0f / 0.15f);
    };
    rbf3(dcc, 0);
    rbf3(dvv, 3);
    rbf3(dcv, 6);
    rbf3(dvc, 9);
  }
  __syncthreads();

  // ---------------- kemb = (ef @ ic_wef) * ic_pat[pattern] ----------------
  float wef[12];
#pragma unroll
  for (int q = 0; q < 12; ++q) wef[q] = ic_wef[q * HD + t];
  const float p1v = ic_pat[HD + t];
  const float p2v = ic_pat[2 * HD + t];
  float kreg[25];
#pragma unroll
  for (int p = 0; p < 25; ++p) {
    const float4 ea = *reinterpret_cast<const float4*>(&efb[wv][p][0]);
    const float4 eb = *reinterpret_cast<const float4*>(&efb[wv][p][4]);
    const float4 ec = *reinterpret_cast<const float4*>(&efb[wv][p][8]);
    float s = ea.x * wef[0];
    s = fmaf(ea.y, wef[1], s);
    s = fmaf(ea.z, wef[2], s);
    s = fmaf(ea.w, wef[3], s);
    s = fmaf(eb.x, wef[4], s);
    s = fmaf(eb.y, wef[5], s);
    s = fmaf(eb.z, wef[6], s);
    s = fmaf(eb.w, wef[7], s);
    s = fmaf(ec.x, wef[8], s);
    s = fmaf(ec.y, wef[9], s);
    s = fmaf(ec.z, wef[10], s);
    s = fmaf(ec.w, wef[11], s);
    s *= ((p % 6) == 0) ? p2v : p1v;  // diag tuples (0,6,12,18,24) -> pattern 2
    kreg[p] = s;
    xb0[wv][p][t] = s;
  }
  __syncthreads();

  // ---------------- three branch MLPs (sm, k0, k1) ----------------
  float smr[25], k0r[25], k1r[25];
#define BRANCH(bidx, dst)                                                     \
  do {                                                                        \
    float acc[25];                                                            \
    const float bb1 = br_b1[(bidx) * HD + t];                                 \
    _Pragma("unroll") for (int r = 0; r < 25; ++r) acc[r] = bb1;              \
    mmk<25>(&xb0[wv][0][0], br_w1 + (bidx) * HD * HD, t, acc);                \
    __syncthreads();                                                          \
    _Pragma("unroll") for (int r = 0; r < 25; ++r) xb1[wv][r][t] =            \
        fmaxf(acc[r], 0.0f);                                                  \
    __syncthreads();                                                          \
    const float bb2 = br_b2[(bidx) * HD + t];                                 \
    _Pragma("unroll") for (int r = 0; r < 25; ++r) acc[r] = bb2;              \
    mmk<25>(&xb1[wv][0][0], br_w2 + (bidx) * HD * HD, t, acc);                \
    _Pragma("unroll") for (int r = 0; r < 25; ++r) (dst)[r] =                 \
        fmaxf(acc[r], 0.0f);                                                  \
  } while (0)

  BRANCH(0, smr);
  BRANCH(1, k0r);
  BRANCH(2, k1r);
#undef BRANCH

  // ---------------- mult einsum (per-lane), z = sm * mult -----------------
  float zt[25];
#pragma unroll
  for (int i = 0; i < 5; ++i) {
#pragma unroll
    for (int k = 0; k < 5; ++k) {
      float m = 0.0f;
#pragma unroll
      for (int j = 0; j < 5; ++j) m = fmaf(k0r[i * 5 + j], k1r[j * 5 + k], m);
      zt[i * 5 + k] = smr[i * 5 + k] * m;
    }
  }
  __syncthreads();
#pragma unroll
  for (int r = 0; r < 25; ++r) xb1[wv][r][t] = zt[r];
  __syncthreads();
  {
    float acc[25];
    const float ob = out_b[t];
#pragma unroll
    for (int r = 0; r < 25; ++r) acc[r] = ob;
    mmk<25>(&xb1[wv][0][0], out_w, t, acc);
#pragma unroll
    for (int r = 0; r < 25; ++r) kreg[r] += fmaxf(acc[r], 0.0f);  // residual
  }
  __syncthreads();
#pragma unroll
  for (int r = 0; r < 25; ++r) xb0[wv][r][t] = kreg[r];  // final kemb
  __syncthreads();

  // ---------------- edge model ----------------
  float ef2[20];
  {
    float accA[5], accB[5];
#pragma unroll
    for (int i = 0; i < 5; ++i) {
      accA[i] = 0.0f;
      accB[i] = 0.0f;
    }
    mmk<5>(&hb[wv][0][0], e_w1, t, accA);            // h[row] part
    mmk<5>(&hb[wv][0][0], e_w1 + 64 * HD, t, accB);  // h[col] part
    float accC[25];
#pragma unroll
    for (int r = 0; r < 25; ++r) accC[r] = 0.0f;
    mmk<25>(&xb0[wv][0][0], e_w1 + 129 * HD, t, accC);  // kemb part
    const float wrad = e_w1[128 * HD + t];
    const float eb1 = e_b1[t];
#pragma unroll
    for (int p = 0; p < 20; ++p) {
      const int ei = p >> 2, jj = p & 3;
      const int ej = jj + (jj >= ei ? 1 : 0);
      const float dx = scv[wv][ei * 3 + 0] - scv[wv][ej * 3 + 0];
      const float dy = scv[wv][ei * 3 + 1] - scv[wv][ej * 3 + 1];
      const float dz = scv[wv][ei * 3 + 2] - scv[wv][ej * 3 + 2];
      const float radial = dx * dx + dy * dy + dz * dz;
      const float pre = accA[ei] + accB[ej] + radial * wrad + accC[ei * 5 + ej] + eb1;
      xb1[wv][p][t] = fmaxf(pre, 0.0f);
    }
    __syncthreads();
    float acc2[20];
    const float eb2 = e_b2[t];
#pragma unroll
    for (int p = 0; p < 20; ++p) acc2[p] = eb2;
    mmk<20>(&xb1[wv][0][0], e_w2, t, acc2);
#pragma unroll
    for (int p = 0; p < 20; ++p) ef2[p] = fmaxf(acc2[p], 0.0f);
  }
  __syncthreads();
#pragma unroll
  for (int p = 0; p < 20; ++p) xb0[wv][p][t] = ef2[p];  // edge_feat broadcastable
  __syncthreads();

  // ---------------- coord scalar per edge: cmat ----------------
  float cm[20];
  {
    float acc[20];
    const float cb = c_b1[t];
#pragma unroll
    for (int p = 0; p < 20; ++p) acc[p] = cb;
    mmk<20>(&xb0[wv][0][0], c_w1, t, acc);
    const float cw2 = c_w2[t];
#pragma unroll
    for (int p = 0; p < 20; ++p) cm[p] = wsum64(fmaxf(acc[p], 0.0f) * cw2);
  }

  // ---------------- vel scalar per node: vmat ----------------
  float vm[5];
  {
    float acc[5];
    const float vb1 = v_b1[t];
#pragma unroll
    for (int i = 0; i < 5; ++i) acc[i] = vb1;
    mmk<5>(&hb[wv][0][0], v_w1, t, acc);
    const float vw2 = v_w2[t];
    const float vb2 = v_b2[0];
#pragma unroll
    for (int i = 0; i < 5; ++i) vm[i] = wsum64(fmaxf(acc[i], 0.0f) * vw2) + vb2;
  }

  // ---------------- coord output (15 values, computed uniformly) ----------
  float coutreg = 0.0f;
#pragma unroll
  for (int i = 0; i < 5; ++i) {
#pragma unroll
    for (int d = 0; d < 3; ++d) {
      const float ci = scv[wv][i * 3 + d];
      float s = 0.0f;
#pragma unroll
      for (int jj = 0; jj < 4; ++jj) {
        const int j = jj + (jj >= i ? 1 : 0);
        float tr = (ci - scv[wv][j * 3 + d]) * cm[i * 4 + jj];
        tr = fminf(fmaxf(tr, -100.0f), 100.0f);
        s += tr;
      }
      const float val = ci + 0.25f * s + scv[wv][16 + i * 3 + d] * vm[i];
      if (t == i * 3 + d) coutreg = val;
    }
  }

  // ---------------- node model ----------------
#pragma unroll
  for (int i = 0; i < 5; ++i)
    xb1[wv][i][t] = ef2[4 * i] + ef2[4 * i + 1] + ef2[4 * i + 2] + ef2[4 * i + 3];  // nagg
  __syncthreads();
  float o5[5];
  {
    float acc[5];
    const float nb1 = n_b1[t];
#pragma unroll
    for (int i = 0; i < 5; ++i) acc[i] = nb1;
    mmk<5>(&hb[wv][0][0], n_w1, t, acc);
    mmk<5>(&xb1[wv][0][0], n_w1 + 64 * HD, t, acc);
    __syncthreads();
#pragma unroll
    for (int i = 0; i < 5; ++i) xb0[wv][i][t] = fmaxf(acc[i], 0.0f);
    __syncthreads();
    const float nb2 = n_b2[t];
#pragma unroll
    for (int i = 0; i < 5; ++i) o5[i] = nb2;
    mmk<5>(&xb0[wv][0][0], n_w2, t, o5);  // NOTE: no outer activation
  }

  if (active) {
#pragma unroll
    for (int i = 0; i < 5; ++i) hout[(g * 5 + i) * HD + t] = hreg[i] + o5[i];
    if (t < 15) cout[g * 15 + t] = coutreg;
  }
}

extern "C" void kernel_launch(void* const* d_in, const int* in_sizes, int n_in,
                              void* d_out, int out_size, void* d_ws, size_t ws_size,
                              hipStream_t stream) {
  (void)d_ws;
  (void)ws_size;
  if (n_in < 27) return;
  const float* gh    = (const float*)d_in[0];
  const float* coord = (const float*)d_in[1];
  const float* vel   = (const float*)d_in[2];
  // d_in[3] = edge_index: structure is implied (all ordered pairs per 5-node graph)
  const float* e_w1 = (const float*)d_in[4];
  const float* e_b1 = (const float*)d_in[5];
  const float* e_w2 = (const float*)d_in[6];
  const float* e_b2 = (const float*)d_in[7];
  const float* n_w1 = (const float*)d_in[8];
  const float* n_b1 = (const float*)d_in[9];
  const float* n_w2 = (const float*)d_in[10];
  const float* n_b2 = (const float*)d_in[11];
  const float* c_w1 = (const float*)d_in[12];
  const float* c_b1 = (const float*)d_in[13];
  const float* c_w2 = (const float*)d_in[14];
  const float* v_w1 = (const float*)d_in[15];
  const float* v_b1 = (const float*)d_in[16];
  const float* v_w2 = (const float*)d_in[17];
  const float* v_b2 = (const float*)d_in[18];
  const float* ic_wef = (const float*)d_in[19];
  const float* ic_pat = (const float*)d_in[20];
  const float* br_w1 = (const float*)d_in[21];
  const float* br_b1 = (const float*)d_in[22];
  const float* br_w2 = (const float*)d_in[23];
  const float* br_b2 = (const float*)d_in[24];
  const float* out_w = (const float*)d_in[25];
  const float* out_b = (const float*)d_in[26];

  const int N = in_sizes[0] / HD;  // 100000
  const int B = N / 5;             // 20000 graphs
  float* hout = (float*)d_out;
  float* cout = (float*)d_out + (size_t)N * HD;

  const int blocks = (B + WPB - 1) / WPB;
  egcl_fused<<<blocks, 64 * WPB, 0, stream>>>(
      gh, coord, vel, e_w1, e_b1, e_w2, e_b2, n_w1, n_b1, n_w2, n_b2, c_w1,
      c_b1, c_w2, v_w1, v_b1, v_w2, v_b2, ic_wef, ic_pat, br_w1, br_b1, br_w2,
      br_b2, out_w, out_b, hout, cout, B);
}

// Round 2
// 409.241 us; speedup vs baseline: 3.1320x; 3.1320x over previous
//
#include <hip/hip_runtime.h>
#include <math.h>

#define HD 64
#define WPB 4

typedef unsigned short u16;
typedef unsigned int u32;
typedef __attribute__((ext_vector_type(8))) short short8;
typedef __attribute__((ext_vector_type(4))) float f32x4;

__device__ __forceinline__ u16 f2bf(float f) {
  u32 u = __float_as_uint(f);
  u32 r = (u + 0x7FFFu + ((u >> 16) & 1u)) >> 16;  // RNE
  return (u16)r;
}
__device__ __forceinline__ float bf2f(u16 x) {
  return __uint_as_float(((u32)x) << 16);
}
// swizzled ushort index for bf16 [32][64] (or [16][64]) LDS tiles
__device__ __forceinline__ int uswz(int row, int col) {
  return ((row << 6) | col) ^ ((row & 7) << 3);
}
__device__ __forceinline__ void wfence() {
  __builtin_amdgcn_sched_barrier(0);
  asm volatile("s_waitcnt lgkmcnt(0)" ::: "memory");
  __builtin_amdgcn_sched_barrier(0);
}

template <int MT>
__device__ __forceinline__ void zacc(f32x4 (*acc)[4]) {
#pragma unroll
  for (int a_ = 0; a_ < MT; ++a_)
#pragma unroll
    for (int b_ = 0; b_ < 4; ++b_) {
      f32x4 z = {0.0f, 0.0f, 0.0f, 0.0f};
      acc[a_][b_] = z;
    }
}

// acc[mt][nt] += A(M x 64, LDS swizzled bf16) @ W(64x64, prepacked [n][k] bf16)
template <int MT>
__device__ __forceinline__ void mm(const u16* A_, const u16* __restrict__ WT,
                                   f32x4 (*acc)[4], int lane) {
  const int c15 = lane & 15;
  const int q8 = (lane >> 4) * 8;
  short8 b[4][2];
#pragma unroll
  for (int nt = 0; nt < 4; ++nt)
#pragma unroll
    for (int s = 0; s < 2; ++s)
      b[nt][s] = *reinterpret_cast<const short8*>(WT + (nt * 16 + c15) * 64 + s * 32 + q8);
#pragma unroll
  for (int mt = 0; mt < MT; ++mt) {
#pragma unroll
    for (int s = 0; s < 2; ++s) {
      const int row = mt * 16 + c15;
      const short8 a = *reinterpret_cast<const short8*>(A_ + uswz(row, s * 32 + q8));
#pragma unroll
      for (int nt = 0; nt < 4; ++nt)
        acc[mt][nt] = __builtin_amdgcn_mfma_f32_16x16x32_bf16(a, b[nt][s], acc[mt][nt], 0, 0, 0);
    }
  }
}

// store frags: D = [relu](acc + bias) as bf16 into swizzled LDS tile
template <int MT, bool RELU>
__device__ __forceinline__ void epi(u16* D_, f32x4 (*acc)[4],
                                    const float* __restrict__ bias, int lane) {
  const int c15 = lane & 15, q = lane >> 4;
#pragma unroll
  for (int nt = 0; nt < 4; ++nt) {
    const int col = nt * 16 + c15;
    const float bb = bias ? bias[col] : 0.0f;
#pragma unroll
    for (int mt = 0; mt < MT; ++mt)
#pragma unroll
      for (int i = 0; i < 4; ++i) {
        const int row = mt * 16 + q * 4 + i;
        float v = acc[mt][nt][i] + bb;
        if (RELU) v = fmaxf(v, 0.0f);
        D_[uswz(row, col)] = f2bf(v);
      }
  }
}

// ---- pre-pass: pack all 64x64 weight blocks to bf16 transposed [n][k] ----
__global__ __launch_bounds__(256) void prepack(
    const float* __restrict__ br_w1, const float* __restrict__ br_w2,
    const float* __restrict__ out_w, const float* __restrict__ e_w1,
    const float* __restrict__ e_w2, const float* __restrict__ c_w1,
    const float* __restrict__ v_w1, const float* __restrict__ n_w1,
    const float* __restrict__ n_w2, u16* __restrict__ W) {
  const int m = blockIdx.x;
  const float* src;
  switch (m) {
    case 0: src = br_w1; break;
    case 1: src = br_w1 + 4096; break;
    case 2: src = br_w1 + 8192; break;
    case 3: src = br_w2; break;
    case 4: src = br_w2 + 4096; break;
    case 5: src = br_w2 + 8192; break;
    case 6: src = out_w; break;
    case 7: src = e_w1; break;            // h[row] rows 0-63
    case 8: src = e_w1 + 64 * 64; break;  // h[col] rows 64-127
    case 9: src = e_w1 + 129 * 64; break; // kemb rows 129-192
    case 10: src = e_w2; break;
    case 11: src = c_w1; break;
    case 12: src = v_w1; break;
    case 13: src = n_w1; break;            // h half
    case 14: src = n_w1 + 64 * 64; break;  // nagg half
    default: src = n_w2; break;
  }
  u16* dst = W + m * 4096;
  for (int e = threadIdx.x; e < 4096; e += blockDim.x) {
    const int n = e >> 6, k = e & 63;
    dst[e] = f2bf(src[k * 64 + n]);
  }
}

__global__ __launch_bounds__(64 * WPB, 2) void egcl_mfma(
    const float* __restrict__ gh, const float* __restrict__ gcoord,
    const float* __restrict__ gvel, const u16* __restrict__ W,
    const float* __restrict__ e_w1, const float* __restrict__ e_b1,
    const float* __restrict__ e_b2,
    const float* __restrict__ n_b1, const float* __restrict__ n_b2,
    const float* __restrict__ c_b1, const float* __restrict__ c_w2,
    const float* __restrict__ v_b1, const float* __restrict__ v_w2,
    const float* __restrict__ v_b2,
    const float* __restrict__ ic_wef, const float* __restrict__ ic_pat,
    const float* __restrict__ br_b1, const float* __restrict__ br_b2,
    const float* __restrict__ out_b,
    float* __restrict__ hout, float* __restrict__ cout, int B) {
  __shared__ __align__(16) u16 sK[WPB][2048];
  __shared__ __align__(16) u16 sT[WPB][2048];
  __shared__ __align__(16) u16 sU0[WPB][2048];
  __shared__ __align__(16) u16 sU1[WPB][2048];
  __shared__ __align__(16) u16 sH[WPB][1024];
  __shared__ float sEF[WPB][300];
  __shared__ float sSCV[WPB][32];
  __shared__ float sRED[WPB][64];

  const int t = threadIdx.x & 63;
  const int wv = threadIdx.x >> 6;
  const int g = blockIdx.x * WPB + wv;
  if (g >= B) return;  // waves are independent: no block barriers anywhere

  u16* K_ = sK[wv];
  u16* T_ = sT[wv];
  u16* U0_ = sU0[wv];
  u16* U1_ = sU1[wv];
  u16* H_ = sH[wv];
  float* EF = sEF[wv];
  float* SCV = sSCV[wv];
  float* RED = sRED[wv];
  const int c15 = t & 15, q = t >> 4;
#define WT(m) (W + (m) * 4096)

  // ---------------- load h / coord / vel ----------------
  float hreg[5];
#pragma unroll
  for (int i = 0; i < 5; ++i) {
    const float hv = gh[(g * 5 + i) * HD + t];
    hreg[i] = hv;
    H_[uswz(i, t)] = f2bf(hv);
  }
  if (t < 15) SCV[t] = gcoord[g * 15 + t];
  if (t >= 16 && t < 31) SCV[t] = gvel[g * 15 + (t - 16)];
  wfence();

  // ---------------- RBF features (lanes 0-24) ----------------
  if (t < 25) {
    const int ti = t / 5, tj = t % 5;
    const float cix = SCV[ti * 3 + 0], ciy = SCV[ti * 3 + 1], ciz = SCV[ti * 3 + 2];
    const float cjx = SCV[tj * 3 + 0], cjy = SCV[tj * 3 + 1], cjz = SCV[tj * 3 + 2];
    const float vix = SCV[16 + ti * 3 + 0], viy = SCV[16 + ti * 3 + 1], viz = SCV[16 + ti * 3 + 2];
    const float vjx = SCV[16 + tj * 3 + 0], vjy = SCV[16 + tj * 3 + 1], vjz = SCV[16 + tj * 3 + 2];
    auto sdist = [](float ax, float ay, float az, float bx, float by, float bz) {
      const float dx = ax - bx, dy = ay - by, dz = az - bz;
      const float sq = dx * dx + dy * dy + dz * dz;
      return (sq > 0.0f) ? sqrtf(sq) : 0.0f;
    };
    const float dcc = sdist(cix, ciy, ciz, cjx, cjy, cjz);
    const float dvv = sdist(vix, viy, viz, vjx, vjy, vjz);
    const float dcv = sdist(cix, ciy, ciz, vjx, vjy, vjz);
    const float dvc = sdist(cjx, cjy, cjz, vix, viy, viz);
    auto rbf3 = [&](float d, int base) {
      const float cut = (d <= 10.0f) ? (0.5f * (cosf(d * 0.31415926535897931f) + 1.0f)) : 0.0f;
      const float e = expf(-0.5f * d);
      const float u0 = e - 4.5399929762484854e-05f;
      const float u1 = e - 0.50002270f;
      const float u2 = e - 1.0f;
      const float BETA = 2.2502043f;
      EF[t * 12 + base + 0] = (cut * expf(-BETA * u0 * u0) - 0.05f) * (1.0f / 0.15f);
      EF[t * 12 + base + 1] = (cut * expf(-BETA * u1 * u1) - 0.05f) * (1.0f / 0.15f);
      EF[t * 12 + base + 2] = (cut * expf(-BETA * u2 * u2) - 0.05f) * (1.0f / 0.15f);
    };
    rbf3(dcc, 0);
    rbf3(dvv, 3);
    rbf3(dcv, 6);
    rbf3(dvc, 9);
  }
  wfence();

  // ---------------- kemb = (ef @ ic_wef) * ic_pat[pattern] ----------------
  {
    float wef[12];
#pragma unroll
    for (int qq = 0; qq < 12; ++qq) wef[qq] = ic_wef[qq * HD + t];
    const float p1v = ic_pat[HD + t], p2v = ic_pat[2 * HD + t];
#pragma unroll
    for (int p = 0; p < 25; ++p) {
      float s = 0.0f;
#pragma unroll
      for (int qq = 0; qq < 12; ++qq) s = fmaf(EF[p * 12 + qq], wef[qq], s);
      s *= ((p % 6) == 0) ? p2v : p1v;
      K_[uswz(p, t)] = f2bf(s);
    }
  }
  wfence();

  f32x4 acc2[2][4];
  f32x4 acc1[1][4];

  // ---------------- branch k0 (idx 1), k1 (idx 2) ----------------
  zacc<2>(acc2); mm<2>(K_, WT(1), acc2, t); wfence();
  epi<2, true>(T_, acc2, br_b1 + 64, t); wfence();
  zacc<2>(acc2); mm<2>(T_, WT(4), acc2, t); wfence();
  epi<2, true>(U0_, acc2, br_b2 + 64, t); wfence();

  zacc<2>(acc2); mm<2>(K_, WT(2), acc2, t); wfence();
  epi<2, true>(T_, acc2, br_b1 + 128, t); wfence();
  zacc<2>(acc2); mm<2>(T_, WT(5), acc2, t); wfence();
  epi<2, true>(U1_, acc2, br_b2 + 128, t); wfence();

  // ---------------- einsum mult (column mode), store to U0_ ----------------
  {
    float k0c[25], k1c[25];
#pragma unroll
    for (int p = 0; p < 25; ++p) {
      k0c[p] = bf2f(U0_[uswz(p, t)]);
      k1c[p] = bf2f(U1_[uswz(p, t)]);
    }
    float mu[25];
#pragma unroll
    for (int i = 0; i < 5; ++i)
#pragma unroll
      for (int k = 0; k < 5; ++k) {
        float m = 0.0f;
#pragma unroll
        for (int j = 0; j < 5; ++j) m = fmaf(k0c[i * 5 + j], k1c[j * 5 + k], m);
        mu[i * 5 + k] = m;
      }
    wfence();
#pragma unroll
    for (int p = 0; p < 25; ++p) U0_[uswz(p, t)] = f2bf(mu[p]);
  }
  wfence();

  // ---------------- branch sm (idx 0), z = relu(sm)*mult ----------------
  zacc<2>(acc2); mm<2>(K_, WT(0), acc2, t); wfence();
  epi<2, true>(T_, acc2, br_b1, t); wfence();
  zacc<2>(acc2); mm<2>(T_, WT(3), acc2, t); wfence();
  {
#pragma unroll
    for (int nt = 0; nt < 4; ++nt) {
      const int col = nt * 16 + c15;
      const float bb = br_b2[col];
#pragma unroll
      for (int mt = 0; mt < 2; ++mt)
#pragma unroll
        for (int i = 0; i < 4; ++i) {
          const int row = mt * 16 + q * 4 + i;
          const int ix = uswz(row, col);
          const float sv = fmaxf(acc2[mt][nt][i] + bb, 0.0f);
          T_[ix] = f2bf(sv * bf2f(U0_[ix]));
        }
    }
  }
  wfence();

  // ---------------- out_w + residual into kemb (frag mode) ----------------
  zacc<2>(acc2); mm<2>(T_, WT(6), acc2, t); wfence();
  {
#pragma unroll
    for (int nt = 0; nt < 4; ++nt) {
      const int col = nt * 16 + c15;
      const float ob = out_b[col];
#pragma unroll
      for (int mt = 0; mt < 2; ++mt)
#pragma unroll
        for (int i = 0; i < 4; ++i) {
          const int row = mt * 16 + q * 4 + i;
          const int ix = uswz(row, col);
          const float v = fmaxf(acc2[mt][nt][i] + ob, 0.0f) + bf2f(K_[ix]);
          K_[ix] = f2bf(v);
        }
    }
  }
  wfence();

  // ---------------- edge model: accC / accA / accB ----------------
  zacc<2>(acc2); mm<2>(K_, WT(9), acc2, t); wfence();
  epi<2, false>(T_, acc2, nullptr, t); wfence();
  zacc<1>(acc1); mm<1>(H_, WT(7), acc1, t); wfence();
  epi<1, false>(U0_, acc1, nullptr, t); wfence();
  zacc<1>(acc1); mm<1>(H_, WT(8), acc1, t); wfence();
  epi<1, false>(U1_, acc1, nullptr, t); wfence();

  // edge assembly (column mode): pre-act -> relu -> stage into U1_
  {
    const float eb1v = e_b1[t];
    const float wradv = e_w1[128 * HD + t];
    float aAc[5], aBc[5];
#pragma unroll
    for (int i = 0; i < 5; ++i) {
      aAc[i] = bf2f(U0_[uswz(i, t)]);
      aBc[i] = bf2f(U1_[uswz(i, t)]);
    }
    float ec[20];
#pragma unroll
    for (int p = 0; p < 20; ++p) {
      const int i = p >> 2, jj = p & 3;
      const int j = jj + (jj >= i ? 1 : 0);
      const float dx = SCV[i * 3 + 0] - SCV[j * 3 + 0];
      const float dy = SCV[i * 3 + 1] - SCV[j * 3 + 1];
      const float dz = SCV[i * 3 + 2] - SCV[j * 3 + 2];
      const float radial = dx * dx + dy * dy + dz * dz;
      const float cc = bf2f(T_[uswz(i * 5 + j, t)]);
      ec[p] = fmaxf(aAc[i] + aBc[j] + radial * wradv + cc + eb1v, 0.0f);
    }
    wfence();
#pragma unroll
    for (int p = 0; p < 20; ++p) U1_[uswz(p, t)] = f2bf(ec[p]);
  }
  wfence();

  // e_w2 -> edge_feat (relu) staged in T_
  zacc<2>(acc2); mm<2>(U1_, WT(10), acc2, t); wfence();
  epi<2, true>(T_, acc2, e_b2, t); wfence();

  // nagg (column mode) staged into U0_ rows 0-4
#pragma unroll
  for (int i = 0; i < 5; ++i) {
    float na = 0.0f;
#pragma unroll
    for (int jj = 0; jj < 4; ++jj) na += bf2f(T_[uswz(4 * i + jj, t)]);
    U0_[uswz(i, t)] = f2bf(na);
  }
  wfence();

  // ---------------- coord scalar per edge (c-model) ----------------
  zacc<2>(acc2); mm<2>(T_, WT(11), acc2, t); wfence();
  {
    float cw2c[4], cb1c[4];
#pragma unroll
    for (int nt = 0; nt < 4; ++nt) {
      cw2c[nt] = c_w2[nt * 16 + c15];
      cb1c[nt] = c_b1[nt * 16 + c15];
    }
#pragma unroll
    for (int mt = 0; mt < 2; ++mt)
#pragma unroll
      for (int i = 0; i < 4; ++i) {
        float s = 0.0f;
#pragma unroll
        for (int nt = 0; nt < 4; ++nt)
          s += fmaxf(acc2[mt][nt][i] + cb1c[nt], 0.0f) * cw2c[nt];
#pragma unroll
        for (int m_ = 1; m_ < 16; m_ <<= 1) s += __shfl_xor(s, m_, 64);
        if (c15 == 0) RED[mt * 16 + q * 4 + i] = s;
      }
  }
  wfence();

  // ---------------- vel scalar per node (v-model) ----------------
  zacc<1>(acc1); mm<1>(H_, WT(12), acc1, t); wfence();
  {
    float vw2c[4], vb1c[4];
#pragma unroll
    for (int nt = 0; nt < 4; ++nt) {
      vw2c[nt] = v_w2[nt * 16 + c15];
      vb1c[nt] = v_b1[nt * 16 + c15];
    }
#pragma unroll
    for (int i = 0; i < 4; ++i) {
      float s = 0.0f;
#pragma unroll
      for (int nt = 0; nt < 4; ++nt)
        s += fmaxf(acc1[0][nt][i] + vb1c[nt], 0.0f) * vw2c[nt];
#pragma unroll
      for (int m_ = 1; m_ < 16; m_ <<= 1) s += __shfl_xor(s, m_, 64);
      if (c15 == 0) RED[32 + q * 4 + i] = s;
    }
  }
  wfence();

  float cm[20], vm[5];
#pragma unroll
  for (int p = 0; p < 20; ++p) cm[p] = RED[p];
  const float vb2 = v_b2[0];
#pragma unroll
  for (int i = 0; i < 5; ++i) vm[i] = RED[32 + i] + vb2;

  // ---------------- coord output ----------------
  float coutreg = 0.0f;
#pragma unroll
  for (int i = 0; i < 5; ++i) {
#pragma unroll
    for (int d = 0; d < 3; ++d) {
      const float ci = SCV[i * 3 + d];
      float s = 0.0f;
#pragma unroll
      for (int jj = 0; jj < 4; ++jj) {
        const int j = jj + (jj >= i ? 1 : 0);
        float tr = (ci - SCV[j * 3 + d]) * cm[i * 4 + jj];
        tr = fminf(fmaxf(tr, -100.0f), 100.0f);
        s += tr;
      }
      const float val = ci + 0.25f * s + SCV[16 + i * 3 + d] * vm[i];
      if (t == i * 3 + d) coutreg = val;
    }
  }

  // ---------------- node model ----------------
  zacc<1>(acc1);
  mm<1>(H_, WT(13), acc1, t);
  mm<1>(U0_, WT(14), acc1, t);
  wfence();
  epi<1, true>(T_, acc1, n_b1, t); wfence();
  zacc<1>(acc1); mm<1>(T_, WT(15), acc1, t); wfence();
  float* O5 = reinterpret_cast<float*>(U1_);  // [16][64] fp32 view
  {
#pragma unroll
    for (int nt = 0; nt < 4; ++nt) {
      const int col = nt * 16 + c15;
      const float nb = n_b2[col];
#pragma unroll
      for (int i = 0; i < 4; ++i) O5[(q * 4 + i) * 64 + col] = acc1[0][nt][i] + nb;
    }
  }
  wfence();

#pragma unroll
  for (int i = 0; i < 5; ++i) hout[(g * 5 + i) * HD + t] = hreg[i] + O5[i * 64 + t];
  if (t < 15) cout[g * 15 + t] = coutreg;
#undef WT
}

extern "C" void kernel_launch(void* const* d_in, const int* in_sizes, int n_in,
                              void* d_out, int out_size, void* d_ws, size_t ws_size,
                              hipStream_t stream) {
  if (n_in < 27) return;
  const float* gh    = (const float*)d_in[0];
  const float* coord = (const float*)d_in[1];
  const float* vel   = (const float*)d_in[2];
  const float* e_w1 = (const float*)d_in[4];
  const float* e_b1 = (const float*)d_in[5];
  const float* e_w2 = (const float*)d_in[6];
  const float* e_b2 = (const float*)d_in[7];
  const float* n_w1 = (const float*)d_in[8];
  const float* n_b1 = (const float*)d_in[9];
  const float* n_w2 = (const float*)d_in[10];
  const float* n_b2 = (const float*)d_in[11];
  const float* c_w1 = (const float*)d_in[12];
  const float* c_b1 = (const float*)d_in[13];
  const float* c_w2 = (const float*)d_in[14];
  const float* v_w1 = (const float*)d_in[15];
  const float* v_b1 = (const float*)d_in[16];
  const float* v_w2 = (const float*)d_in[17];
  const float* v_b2 = (const float*)d_in[18];
  const float* ic_wef = (const float*)d_in[19];
  const float* ic_pat = (const float*)d_in[20];
  const float* br_w1 = (const float*)d_in[21];
  const float* br_b1 = (const float*)d_in[22];
  const float* br_w2 = (const float*)d_in[23];
  const float* br_b2 = (const float*)d_in[24];
  const float* out_w = (const float*)d_in[25];
  const float* out_b = (const float*)d_in[26];

  const int N = in_sizes[0] / HD;  // 100000
  const int B = N / 5;             // 20000 graphs
  float* hout = (float*)d_out;
  float* cout = (float*)d_out + (size_t)N * HD;
  u16* W = (u16*)d_ws;  // 16 matrices x 4096 bf16 = 128 KB

  prepack<<<16, 256, 0, stream>>>(br_w1, br_w2, out_w, e_w1, e_w2, c_w1, v_w1,
                                  n_w1, n_w2, W);

  const int blocks = (B + WPB - 1) / WPB;
  egcl_mfma<<<blocks, 64 * WPB, 0, stream>>>(
      gh, coord, vel, W, e_w1, e_b1, e_b2, n_b1, n_b2, c_b1, c_w2, v_b1, v_w2,
      v_b2, ic_wef, ic_pat, br_b1, br_b2, out_b, hout, cout, B);
}